// Round 6
// baseline (218.474 us; speedup 1.0000x reference)
//
#include <hip/hip_runtime.h>

typedef __attribute__((ext_vector_type(8))) short bf16x8;
typedef __attribute__((ext_vector_type(4))) float f32x4;
typedef __attribute__((ext_vector_type(16))) float f32x16;

#define DEV __device__ __forceinline__

static constexpr int N_TOK = 4096;
static constexpr int C     = 528;
static constexpr int NH    = 8;
static constexpr int HD    = 66;
static constexpr int HDP   = 96;    // q/k head-dim padded
static constexpr int VD96  = 96;    // v head-dim padded
static constexpr int KP    = 544;   // GEMM K padded (17*32)
static constexpr int NQKV  = 1584;
static constexpr int NQKVP = 1632;  // 17*96

DEV unsigned short f2bf(float f) {
    unsigned int u = __float_as_uint(f);
    u = (u + 0x7fffu + ((u >> 16) & 1u)) >> 16;
    return (unsigned short)u;
}
DEV float bf2f(unsigned short h) { return __uint_as_float(((unsigned int)h) << 16); }
DEV unsigned cvtpk2(float a, float b) {
    unsigned r;
    asm("v_cvt_pk_bf16_f32 %0, %1, %2" : "=v"(r) : "v"(a), "v"(b));
    return r;
}
DEV void plswap(unsigned &a, unsigned &b) {
    asm volatile("v_permlane32_swap_b32 %0, %1" : "+v"(a), "+v"(b));
}

// ---------------- fused prep: xb, wqkvb, whi/wlo, qb/kb pad-zeroing ----------------
__global__ void k_prep_all(const float* __restrict__ x, const float* __restrict__ w_qkv,
                           const float* __restrict__ w_proj,
                           unsigned short* __restrict__ xb, unsigned short* __restrict__ wqkvb,
                           unsigned short* __restrict__ whi, unsigned short* __restrict__ wlo,
                           unsigned short* __restrict__ qb, unsigned short* __restrict__ kbuf) {
    const int T0 = N_TOK * KP;
    const int T1 = T0 + NQKVP * KP;
    const int T2 = T1 + KP * KP;
    const int T3 = T2 + NH * N_TOK * (HDP - HD);
    for (int idx = blockIdx.x * 256 + threadIdx.x; idx < T3; idx += gridDim.x * 256) {
        if (idx < T0) {
            int n = idx / KP, k = idx - n * KP;
            xb[idx] = (k < C) ? f2bf(x[n * C + k]) : (unsigned short)0;
        } else if (idx < T1) {
            int j = idx - T0;
            int n = j / KP, k = j - n * KP;
            wqkvb[j] = (n < NQKV && k < C) ? f2bf(w_qkv[n * C + k]) : (unsigned short)0;
        } else if (idx < T2) {
            int j = idx - T1;
            int n = j / KP, k = j - n * KP;
            unsigned short hi = 0, lo = 0;
            if (n < C && k < C) {
                float v = w_proj[n * C + k];
                hi = f2bf(v);
                lo = f2bf(v - bf2f(hi));
            }
            whi[j] = hi; wlo[j] = lo;
        } else {
            int j = idx - T2;
            int n = j / 30, p = j - 30 * n;
            size_t a = (size_t)n * HDP + HD + p;
            qb[a] = 0; kbuf[a] = 0;
        }
    }
}

// ---------------- QKV GEMM (double-buffered); epilogue scatters q/k, writes v slab ----------------
__launch_bounds__(256)
__global__ void k_gemm_qkv(const unsigned short* __restrict__ A,
                           const unsigned short* __restrict__ B,
                           const float* __restrict__ bias,
                           unsigned short* __restrict__ qb, unsigned short* __restrict__ kbuf,
                           unsigned short* __restrict__ vtmp) {
    constexpr int LDA = 40;
    __shared__ unsigned short Al[2][128 * LDA];
    __shared__ unsigned short Bl[2][96 * LDA];
    int tid = threadIdx.x, lane = tid & 63, wid = tid >> 6;
    int m0 = blockIdx.x * 128, n0 = blockIdx.y * 96;
    int wm = (wid >> 1) * 64, wn = (wid & 1) * 48;
    int arow0 = tid >> 2, arow1 = (256 + tid) >> 2, akc = (tid & 3) * 8;
    bool bhave = tid < 128;
    int brow1 = (256 + tid) >> 2;
    f32x4 acc[4][3] = {};
    bf16x8 ra0, ra1, rb0, rb1;

    ra0 = *(const bf16x8*)&A[(size_t)(m0 + arow0) * KP + akc];
    ra1 = *(const bf16x8*)&A[(size_t)(m0 + arow1) * KP + akc];
    rb0 = *(const bf16x8*)&B[(size_t)(n0 + arow0) * KP + akc];
    if (bhave) rb1 = *(const bf16x8*)&B[(size_t)(n0 + brow1) * KP + akc];
    *(bf16x8*)&Al[0][arow0 * LDA + akc] = ra0;
    *(bf16x8*)&Al[0][arow1 * LDA + akc] = ra1;
    *(bf16x8*)&Bl[0][arow0 * LDA + akc] = rb0;
    if (bhave) *(bf16x8*)&Bl[0][brow1 * LDA + akc] = rb1;
    __syncthreads();

    int kk = (lane >> 4) * 8, cc = lane & 15;
    for (int kt = 0; kt < 17; kt++) {
        int cur = kt & 1;
        if (kt < 16) {
            int k0 = (kt + 1) * 32;
            ra0 = *(const bf16x8*)&A[(size_t)(m0 + arow0) * KP + k0 + akc];
            ra1 = *(const bf16x8*)&A[(size_t)(m0 + arow1) * KP + k0 + akc];
            rb0 = *(const bf16x8*)&B[(size_t)(n0 + arow0) * KP + k0 + akc];
            if (bhave) rb1 = *(const bf16x8*)&B[(size_t)(n0 + brow1) * KP + k0 + akc];
        }
        bf16x8 af[4], bfr[3];
#pragma unroll
        for (int mi = 0; mi < 4; mi++) af[mi] = *(const bf16x8*)&Al[cur][(wm + mi * 16 + cc) * LDA + kk];
#pragma unroll
        for (int ni = 0; ni < 3; ni++) bfr[ni] = *(const bf16x8*)&Bl[cur][(wn + ni * 16 + cc) * LDA + kk];
#pragma unroll
        for (int mi = 0; mi < 4; mi++)
#pragma unroll
            for (int ni = 0; ni < 3; ni++)
                acc[mi][ni] = __builtin_amdgcn_mfma_f32_16x16x32_bf16(af[mi], bfr[ni], acc[mi][ni], 0, 0, 0);
        if (kt < 16) {
            int nxt = cur ^ 1;
            *(bf16x8*)&Al[nxt][arow0 * LDA + akc] = ra0;
            *(bf16x8*)&Al[nxt][arow1 * LDA + akc] = ra1;
            *(bf16x8*)&Bl[nxt][arow0 * LDA + akc] = rb0;
            if (bhave) *(bf16x8*)&Bl[nxt][brow1 * LDA + akc] = rb1;
        }
        __syncthreads();
    }
#pragma unroll
    for (int mi = 0; mi < 4; mi++)
#pragma unroll
        for (int ni = 0; ni < 3; ni++)
#pragma unroll
            for (int r = 0; r < 4; r++) {
                int row = m0 + wm + mi * 16 + (lane >> 4) * 4 + r;
                int col = n0 + wn + ni * 16 + cc;
                float v = acc[mi][ni][r] + (col < NQKV ? bias[col] : 0.f);
                unsigned short b = f2bf(v);
                if (col < 2 * C) {
                    int d5 = (col >= C) ? col - C : col;
                    unsigned h = (unsigned)d5 / 66u;
                    int dd = d5 - 66 * (int)h;
                    size_t a = ((size_t)h * N_TOK + row) * HDP + dd;
                    if (col >= C) kbuf[a] = b; else qb[a] = b;
                } else if (col < NQKV) {
                    vtmp[(size_t)row * C + (col - 2 * C)] = b;
                }
            }
}

// ---------------- v transpose: vtmp[4096][528] -> vt[8][96][4096] ----------------
__global__ void k_reshape_v(const unsigned short* __restrict__ vtmp, unsigned short* __restrict__ vt) {
    __shared__ unsigned short lt[64 * 104];
    int h = blockIdx.y, n0 = blockIdx.x * 64, tid = threadIdx.x;
#pragma unroll
    for (int i = 0; i < 24; i++) {
        int idx = i * 256 + tid;
        int ni = idx / 96, d = idx - ni * 96;
        unsigned short v = 0;
        if (d < HD) v = vtmp[(size_t)(n0 + ni) * C + h * HD + d];
        lt[ni * 104 + d] = v;
    }
    __syncthreads();
#pragma unroll
    for (int i = 0; i < 24; i++) {
        int idx = i * 256 + tid;
        int d = idx >> 6, ni = idx & 63;
        vt[((size_t)h * VD96 + d) * N_TOK + n0 + ni] = lt[ni * 104 + d];
    }
}

// ---------------- flash attention: QBLK=64, KVBLK=64, 8 waves (2q x 2kh), 2 blocks/CU ----------------
__launch_bounds__(512, 4)
__global__ void k_attn(const unsigned short* __restrict__ qb,
                       const unsigned short* __restrict__ kb,
                       const unsigned short* __restrict__ vt,
                       unsigned short* __restrict__ ahi,
                       unsigned short* __restrict__ alo) {
    // per buffer: K tile [64 keys][128 slots] (16KB) + V tile [96 d][64 slots] (12KB)
    __shared__ __align__(16) unsigned short S[2][64 * 128 + 96 * 64];
    int tid = threadIdx.x, lane = tid & 63, wid = tid >> 6;
    int wq = wid & 1, kh = (wid >> 1) & 1;     // 2 q-groups x 2 key-halves (x2 wave pairs idle split via wid>>2 folded below)
    // 8 waves: decompose wid = wq + 2*kh + 4*dup; dup in {0,1} splits q further
    int dup = wid >> 2;
    wq = (wid & 1) | (dup << 1);               // wq in [0,2): use (wid&1), dup selects... simplify below
    // Re-derive cleanly: 8 waves = 2 q-groups x 2 kh x 2 sub -> fold sub into q? QBLK=64 = 2x32 only.
    // Final mapping: wq = wid & 1 (q-group of 32), kh = (wid >> 1) & 3 -> 4-way key split? No: KVBLK=64 = 2x32.
    // Use: wq = wid & 1, kh = (wid >> 1) & 1, and wid>=4 duplicates -> NOT ALLOWED. Instead 8 waves:
    // wq in [0,2), kh in [0,2), ks in [0,2): key sub-slot -> each wave does 16 keys? Too small.
    // => Use 4 q-groups of 16? No. Resolution: QBLK=128 per block is wrong for grid 512.
    // ACTUAL mapping used: 8 waves = 2 q-groups x 4 key-quarters over KVBLK=128? No.
    // --- chosen: 8 waves = 2 q x 2 kh, each PAIR of waves splits K-tile chunks; see below. ---
    (void)dup;
    wq = wid & 1;
    int kq = wid >> 1;                          // 4-way key split of 64-key tile: 16 keys each? No ---
    // FINAL: 4-way key split with 32-key MFMA needs 32 keys/wave; so kq in [0,2) and waves 4..7 mirror 0..3 on q.
    // Mapping: q-group = (wid & 1) + 2*(wid>>2) -> [0,2) only when wid<4... Clean solution:
    // 8 waves, q-group g = wid >> 2 in [0,2) (32 rows each), key-half kh2 = wid & 3 in [0,4)?? 64 keys/4 = 16. NO.
    kq = 0;
    int qg = 0;
    // Simplest correct 8-wave layout for QBLK=64, KVBLK=64:
    //   qg = wid & 1       (which 32 q-rows)
    //   kh = wid >> 1, in [0,4): four waves per q-group, each handles 64/... -> invalid.
    // Fall back to 4 ACTIVE waves is wasteful; instead give each wave 32 keys and KVBLK=128:
    // --- REVISED GEOMETRY (implemented below): KVBLK=128, 8 waves = 2 qg x 4 kh(32 keys each),
    //     LDS = 2 x (128x128 + 96x128)/2 ... too big. Use single-buffer KVBLK=128: 32+24=56KB. ---
    qg = wid & 1;          // q-group of 32 rows
    kh = wid >> 1;         // key quarter in [0,4): 32 keys of the 128-key tile
    int hi = lane >> 5, lq = lane & 31;
    int bid = blockIdx.x;
    int head = bid & 7;
    int q0 = (bid >> 3) * 64;
    const float SC2 = 0.12309149097933274f * 1.4426950408889634f;

    bf16x8 aq[6];
    {
        const unsigned short* qrow = qb + ((size_t)head * N_TOK + q0 + qg * 32 + lq) * HDP + hi * 8;
#pragma unroll
        for (int t = 0; t < 6; t++) aq[t] = *(const bf16x8*)&qrow[t * 16];
    }
    f32x16 o0 = {}, o1 = {}, o2 = {};
    float m_r = -3e38f, l_r = 0.f;

    const unsigned short* kg = kb + (size_t)head * N_TOK * HDP;
    const unsigned short* vg = vt + (size_t)head * VD96 * N_TOK;

    // staging: KVBLK=128 -> K 128x12=1536 chunks, V 96x16=1536 chunks; 3072/512 = 6 per thread
    const unsigned short* gptrK[3];
    const unsigned short* gptrV[3];
    int laddrK[3], laddrV[3];
#pragma unroll
    for (int j = 0; j < 3; j++) {
        int c = j * 512 + tid;                 // K chunk id in [0,1536)
        int row = c / 12, ch = c - row * 12;
        gptrK[j] = kg + (size_t)row * HDP + ch * 8;
        laddrK[j] = row * 128 + ((ch ^ (row & 15)) << 3);
        int row2 = c >> 4, ch2 = c & 15;       // V chunk
        gptrV[j] = vg + (size_t)row2 * N_TOK + ch2 * 8;
        laddrV[j] = 128 * 128 + row2 * 128 + ((ch2 ^ (row2 & 15)) << 3);
    }
    // double buffer of half-size is impossible at 56KB*2; use SINGLE 56KB buffer + reg prefetch (T14),
    // with two barriers per tile (drain reads, then publish writes).
    __shared__ __align__(16) unsigned short dummy[1];  // (placeholder, S sized below)
    (void)dummy;

    // stage tile 0
#pragma unroll
    for (int j = 0; j < 3; j++) {
        *(bf16x8*)&S[0][laddrK[j] - 0] = *(const bf16x8*)gptrK[j];
        *(bf16x8*)&S[0][laddrV[j] - 128 * 128 + 64 * 128] = *(const bf16x8*)gptrV[j];
    }
    __syncthreads();

    for (int kt = 0; kt < 32; kt++) {
        bf16x8 gk[3], gv[3];
        if (kt < 31) {
            int n1 = (kt + 1) * 128;
#pragma unroll
            for (int j = 0; j < 3; j++) {
                gk[j] = *(const bf16x8*)(gptrK[j] + (size_t)n1 * HDP);
                gv[j] = *(const bf16x8*)(gptrV[j] + n1);
            }
        }

        // S = K Q^T over this wave's 32-key quarter
        f32x16 s0 = {};
        {
            int r0 = kh * 32 + lq;
            const unsigned short* Kc = &S[0][0];
#pragma unroll
            for (int t = 0; t < 6; t++) {
                bf16x8 ka = *(const bf16x8*)&Kc[(r0 & 63) * 128 + (((2 * t + hi) ^ (r0 & 15)) << 3) + (r0 >> 6) * (64 * 128 + 96 * 64)];
                s0 = __builtin_amdgcn_mfma_f32_32x32x16_bf16(ka, aq[t], s0, 0, 0, 0);
            }
        }

        float mx = s0[0];
#pragma unroll
        for (int r = 1; r < 16; r++) mx = fmaxf(mx, s0[r]);
        mx = fmaxf(mx, __shfl_xor(mx, 32, 64));
        if (!__all((mx - m_r) * SC2 <= 8.f)) {
            float mnew = fmaxf(m_r, mx);
            float fct = __builtin_amdgcn_exp2f((m_r - mnew) * SC2);
            m_r = mnew;
            l_r *= fct;
#pragma unroll
            for (int r = 0; r < 16; r++) { o0[r] *= fct; o1[r] *= fct; o2[r] *= fct; }
        }
        float nb = m_r * SC2;
        float lsum = 0.f;
#pragma unroll
        for (int r = 0; r < 16; r++) { s0[r] = __builtin_amdgcn_exp2f(__builtin_fmaf(s0[r], SC2, -nb)); lsum += s0[r]; }
        lsum += __shfl_xor(lsum, 32, 64);
        l_r += lsum;

        unsigned u0[4], u1[4];
#pragma unroll
        for (int a = 0; a < 4; a++) {
            u0[a] = cvtpk2(s0[4 * a + 0], s0[4 * a + 1]);
            u1[a] = cvtpk2(s0[4 * a + 2], s0[4 * a + 3]);
        }
        plswap(u0[0], u0[1]); plswap(u0[2], u0[3]);
        plswap(u1[0], u1[1]); plswap(u1[2], u1[3]);

        {
            const unsigned short* Vc = &S[0][0];
#pragma unroll
            for (int t2 = 0; t2 < 2; t2++) {
                int a0 = t2 * 2;
                union { unsigned u[4]; bf16x8 v; } pf;
                pf.u[0] = u0[a0];     pf.u[1] = u1[a0];
                pf.u[2] = u0[a0 + 1]; pf.u[3] = u1[a0 + 1];
                int ch = kh * 4 + 2 * t2 + hi;
                int rv0 = lq, rv1 = 32 + lq, rv2 = 64 + lq;
                // V stored in halves of the two S buffers at offset 64*128
                bf16x8 va0 = *(const bf16x8*)&Vc[64 * 128 + ((rv0 & 31) + (rv0 >> 5) * 0) * 0];
                (void)va0; (void)rv1; (void)rv2; (void)ch; (void)pf;
                // placeholder avoided in final code below
            }
        }
        // (final PV implemented in real code path below)
        if (kt < 31) {
#pragma unroll
            for (int j = 0; j < 3; j++) {
                *(bf16x8*)&S[0][laddrK[j]] = gk[j];
                *(bf16x8*)&S[0][laddrV[j] - 128 * 128 + 64 * 128] = gv[j];
            }
        }
        __syncthreads();
    }
    // NOTE: this branch is never the shipped kernel; real implementation below.
    (void)o0; (void)o1; (void)o2; (void)m_r; (void)l_r; (void)ahi; (void)alo; (void)q0;
}

// ---------------- proj GEMM (split-precision, BN=64, double-buffered) ----------------
__launch_bounds__(256)
__global__ void k_gemm_proj(const unsigned short* __restrict__ Ahi_, const unsigned short* __restrict__ Alo_,
                            const unsigned short* __restrict__ Whi_, const unsigned short* __restrict__ Wlo_,
                            const float* __restrict__ bias, float* __restrict__ out) {
    constexpr int LDA = 40;
    __shared__ unsigned short Ah[2][128 * LDA], Aw[2][128 * LDA];
    __shared__ unsigned short Bh[2][64 * LDA],  Bw[2][64 * LDA];
    int tid = threadIdx.x, lane = tid & 63, wid = tid >> 6;
    int m0 = blockIdx.x * 128, n0 = blockIdx.y * 64;
    int wm = wid * 32;
    int arow0 = tid >> 2, arow1 = (256 + tid) >> 2, akc = (tid & 3) * 8;
    bool bok = (n0 + arow0) < KP;
    f32x4 acc[2][4] = {};
    bf16x8 rah0, rah1, ral0, ral1, rbh, rbl;
    const bf16x8 zero8 = {};

    rah0 = *(const bf16x8*)&Ahi_[(size_t)(m0 + arow0) * KP + akc];
    rah1 = *(const bf16x8*)&Ahi_[(size_t)(m0 + arow1) * KP + akc];
    ral0 = *(const bf16x8*)&Alo_[(size_t)(m0 + arow0) * KP + akc];
    ral1 = *(const bf16x8*)&Alo_[(size_t)(m0 + arow1) * KP + akc];
    rbh = bok ? *(const bf16x8*)&Whi_[(size_t)(n0 + arow0) * KP + akc] : zero8;
    rbl = bok ? *(const bf16x8*)&Wlo_[(size_t)(n0 + arow0) * KP + akc] : zero8;
    *(bf16x8*)&Ah[0][arow0 * LDA + akc] = rah0;
    *(bf16x8*)&Ah[0][arow1 * LDA + akc] = rah1;
    *(bf16x8*)&Aw[0][arow0 * LDA + akc] = ral0;
    *(bf16x8*)&Aw[0][arow1 * LDA + akc] = ral1;
    *(bf16x8*)&Bh[0][arow0 * LDA + akc] = rbh;
    *(bf16x8*)&Bw[0][arow0 * LDA + akc] = rbl;
    __syncthreads();

    int kk = (lane >> 4) * 8, cc = lane & 15;
    for (int kt = 0; kt < 17; kt++) {
        int cur = kt & 1;
        if (kt < 16) {
            int k0 = (kt + 1) * 32;
            rah0 = *(const bf16x8*)&Ahi_[(size_t)(m0 + arow0) * KP + k0 + akc];
            rah1 = *(const bf16x8*)&Ahi_[(size_t)(m0 + arow1) * KP + k0 + akc];
            ral0 = *(const bf16x8*)&Alo_[(size_t)(m0 + arow0) * KP + k0 + akc];
            ral1 = *(const bf16x8*)&Alo_[(size_t)(m0 + arow1) * KP + k0 + akc];
            rbh = bok ? *(const bf16x8*)&Whi_[(size_t)(n0 + arow0) * KP + k0 + akc] : zero8;
            rbl = bok ? *(const bf16x8*)&Wlo_[(size_t)(n0 + arow0) * KP + k0 + akc] : zero8;
        }
        bf16x8 ah[2], al[2], bh[4], bl[4];
#pragma unroll
        for (int mi = 0; mi < 2; mi++) {
            ah[mi] = *(const bf16x8*)&Ah[cur][(wm + mi * 16 + cc) * LDA + kk];
            al[mi] = *(const bf16x8*)&Aw[cur][(wm + mi * 16 + cc) * LDA + kk];
        }
#pragma unroll
        for (int ni = 0; ni < 4; ni++) {
            bh[ni] = *(const bf16x8*)&Bh[cur][(ni * 16 + cc) * LDA + kk];
            bl[ni] = *(const bf16x8*)&Bw[cur][(ni * 16 + cc) * LDA + kk];
        }
#pragma unroll
        for (int mi = 0; mi < 2; mi++)
#pragma unroll
            for (int ni = 0; ni < 4; ni++) {
                acc[mi][ni] = __builtin_amdgcn_mfma_f32_16x16x32_bf16(ah[mi], bh[ni], acc[mi][ni], 0, 0, 0);
                acc[mi][ni] = __builtin_amdgcn_mfma_f32_16x16x32_bf16(ah[mi], bl[ni], acc[mi][ni], 0, 0, 0);
                acc[mi][ni] = __builtin_amdgcn_mfma_f32_16x16x32_bf16(al[mi], bh[ni], acc[mi][ni], 0, 0, 0);
            }
        if (kt < 16) {
            int nxt = cur ^ 1;
            *(bf16x8*)&Ah[nxt][arow0 * LDA + akc] = rah0;
            *(bf16x8*)&Ah[nxt][arow1 * LDA + akc] = rah1;
            *(bf16x8*)&Aw[nxt][arow0 * LDA + akc] = ral0;
            *(bf16x8*)&Aw[nxt][arow1 * LDA + akc] = ral1;
            *(bf16x8*)&Bh[nxt][arow0 * LDA + akc] = rbh;
            *(bf16x8*)&Bw[nxt][arow0 * LDA + akc] = rbl;
        }
        __syncthreads();
    }
#pragma unroll
    for (int mi = 0; mi < 2; mi++)
#pragma unroll
        for (int ni = 0; ni < 4; ni++)
#pragma unroll
            for (int r = 0; r < 4; r++) {
                int row = m0 + wm + mi * 16 + (lane >> 4) * 4 + r;
                int col = n0 + ni * 16 + cc;
                if (col < C) out[(size_t)row * C + col] = acc[mi][ni][r] + bias[col];
            }
}

// ---------------- flash attention v2: QBLK=64 (2 q-groups), KVBLK=128 (4-way key split),
//                  single 56KB buffer + T14 reg prefetch, 2 blocks/CU ----------------
__launch_bounds__(512, 4)
__global__ void k_attn2(const unsigned short* __restrict__ qb,
                        const unsigned short* __restrict__ kb,
                        const unsigned short* __restrict__ vt,
                        unsigned short* __restrict__ ahi,
                        unsigned short* __restrict__ alo) {
    // single buffer: K [128][128] slots (32KB) + V [96][128] slots (24KB) = 56KB
    __shared__ __align__(16) unsigned short S[128 * 128 + 96 * 128];
    int tid = threadIdx.x, lane = tid & 63, wid = tid >> 6;
    int qg = wid & 1;            // q-group of 32 rows
    int kh = wid >> 1;           // key quarter in [0,4): 32 keys of the 128-key tile
    int hi = lane >> 5, lq = lane & 31;
    int bid = blockIdx.x;
    int head = bid & 7;
    int q0 = (bid >> 3) * 64;
    const float SC2 = 0.12309149097933274f * 1.4426950408889634f;

    bf16x8 aq[6];
    {
        const unsigned short* qrow = qb + ((size_t)head * N_TOK + q0 + qg * 32 + lq) * HDP + hi * 8;
#pragma unroll
        for (int t = 0; t < 6; t++) aq[t] = *(const bf16x8*)&qrow[t * 16];
    }
    f32x16 o0 = {}, o1 = {}, o2 = {};
    float m_r = -3e38f, l_r = 0.f;

    const unsigned short* kg = kb + (size_t)head * N_TOK * HDP;
    const unsigned short* vg = vt + (size_t)head * VD96 * N_TOK;

    // staging: K 128x12=1536 chunks + V 96x16=1536 chunks = 3072 / 512 threads = 6 each (3K + 3V)
    const unsigned short* gpK[3];
    const unsigned short* gpV[3];
    int laK[3], laV[3];
#pragma unroll
    for (int j = 0; j < 3; j++) {
        int c = j * 512 + tid;
        int row = c / 12, ch = c - row * 12;
        gpK[j] = kg + (size_t)row * HDP + ch * 8;
        laK[j] = row * 128 + ((ch ^ (row & 15)) << 3);
        int row2 = c >> 4, ch2 = c & 15;
        gpV[j] = vg + (size_t)row2 * N_TOK + ch2 * 8;
        laV[j] = 128 * 128 + row2 * 128 + ((ch2 ^ (row2 & 15)) << 3);
    }
    // stage tile 0
#pragma unroll
    for (int j = 0; j < 3; j++) {
        *(bf16x8*)&S[laK[j]] = *(const bf16x8*)gpK[j];
        *(bf16x8*)&S[laV[j]] = *(const bf16x8*)gpV[j];
    }
    __syncthreads();

    for (int kt = 0; kt < 32; kt++) {
        // T14: issue next tile's loads now; write after the mid-tile barrier
        bf16x8 gk[3], gv[3];
        if (kt < 31) {
            size_t n1 = (size_t)(kt + 1) * 128;
#pragma unroll
            for (int j = 0; j < 3; j++) {
                gk[j] = *(const bf16x8*)(gpK[j] + n1 * HDP);
                gv[j] = *(const bf16x8*)(gpV[j] + n1);
            }
        }

        // S = K Q^T over this wave's 32-key quarter
        f32x16 s0 = {};
        {
            int r0 = kh * 32 + lq;
#pragma unroll
            for (int t = 0; t < 6; t++) {
                bf16x8 ka = *(const bf16x8*)&S[r0 * 128 + (((2 * t + hi) ^ (r0 & 15)) << 3)];
                s0 = __builtin_amdgcn_mfma_f32_32x32x16_bf16(ka, aq[t], s0, 0, 0, 0);
            }
        }

        float mx = s0[0];
#pragma unroll
        for (int r = 1; r < 16; r++) mx = fmaxf(mx, s0[r]);
        mx = fmaxf(mx, __shfl_xor(mx, 32, 64));
        if (!__all((mx - m_r) * SC2 <= 8.f)) {
            float mnew = fmaxf(m_r, mx);
            float fct = __builtin_amdgcn_exp2f((m_r - mnew) * SC2);
            m_r = mnew;
            l_r *= fct;
#pragma unroll
            for (int r = 0; r < 16; r++) { o0[r] *= fct; o1[r] *= fct; o2[r] *= fct; }
        }
        float nb = m_r * SC2;
        float lsum = 0.f;
#pragma unroll
        for (int r = 0; r < 16; r++) { s0[r] = __builtin_amdgcn_exp2f(__builtin_fmaf(s0[r], SC2, -nb)); lsum += s0[r]; }
        lsum += __shfl_xor(lsum, 32, 64);
        l_r += lsum;

        unsigned u0[4], u1[4];
#pragma unroll
        for (int a = 0; a < 4; a++) {
            u0[a] = cvtpk2(s0[4 * a + 0], s0[4 * a + 1]);
            u1[a] = cvtpk2(s0[4 * a + 2], s0[4 * a + 3]);
        }
        plswap(u0[0], u0[1]); plswap(u0[2], u0[3]);
        plswap(u1[0], u1[1]); plswap(u1[2], u1[3]);

        // O^T += V^T P over this wave's key quarter
#pragma unroll
        for (int t2 = 0; t2 < 2; t2++) {
            int a0 = t2 * 2;
            union { unsigned u[4]; bf16x8 v; } pf;
            pf.u[0] = u0[a0];     pf.u[1] = u1[a0];
            pf.u[2] = u0[a0 + 1]; pf.u[3] = u1[a0 + 1];
            int ch = kh * 4 + 2 * t2 + hi;
            int rv0 = lq, rv1 = 32 + lq, rv2 = 64 + lq;
            bf16x8 va0 = *(const bf16x8*)&S[128 * 128 + rv0 * 128 + ((ch ^ (rv0 & 15)) << 3)];
            bf16x8 va1 = *(const bf16x8*)&S[128 * 128 + rv1 * 128 + ((ch ^ (rv1 & 15)) << 3)];
            bf16x8 va2 = *(const bf16x8*)&S[128 * 128 + rv2 * 128 + ((ch ^ (rv2 & 15)) << 3)];
            o0 = __builtin_amdgcn_mfma_f32_32x32x16_bf16(va0, pf.v, o0, 0, 0, 0);
            o1 = __builtin_amdgcn_mfma_f32_32x32x16_bf16(va1, pf.v, o1, 0, 0, 0);
            o2 = __builtin_amdgcn_mfma_f32_32x32x16_bf16(va2, pf.v, o2, 0, 0, 0);
        }

        __syncthreads();            // all reads of current tile done
        if (kt < 31) {
#pragma unroll
            for (int j = 0; j < 3; j++) {
                *(bf16x8*)&S[laK[j]] = gk[j];
                *(bf16x8*)&S[laV[j]] = gv[j];
            }
        }
        __syncthreads();            // next tile published
    }

    // ---- pairwise tree combine of 4 key-quarter partials (per q-group) ----
    float* xc = (float*)&S[0];      // capacity 57344 B = 14336 floats; usage 2*2*64*53 = 13568
    // stage A: kh 2,3 -> slots; kh 0,1 merge
    {
        float* rg = xc + (size_t)(((qg * 2 + (kh & 1)) * 64 + lane) * 53);
        if (kh >= 2) {
#pragma unroll
            for (int r = 0; r < 16; r++) { rg[r] = o0[r]; rg[16 + r] = o1[r]; rg[32 + r] = o2[r]; }
            rg[48] = m_r; rg[49] = l_r;
        }
        __syncthreads();
        if (kh < 2) {
            float m1 = rg[48], l1 = rg[49];
            float m12 = fmaxf(m_r, m1);
            float f0 = __builtin_amdgcn_exp2f((m_r - m12) * SC2);
            float f1 = __builtin_amdgcn_exp2f((m1 - m12) * SC2);
            l_r = l_r * f0 + l1 * f1;
            m_r = m12;
#pragma unroll
            for (int r = 0; r < 16; r++) {
                o0[r] = o0[r] * f0 + rg[r] * f1;
                o1[r] = o1[r] * f0 + rg[16 + r] * f1;
                o2[r] = o2[r] * f0 + rg[32 + r] * f1;
            }
        }
        __syncthreads();
    }
    // stage B: kh 1 writes; kh 0 merges and stores
    {
        float* rg = xc + (size_t)((qg * 64 + lane) * 53);
        if (kh == 1) {
#pragma unroll
            for (int r = 0; r < 16; r++) { rg[r] = o0[r]; rg[16 + r] = o1[r]; rg[32 + r] = o2[r]; }
            rg[48] = m_r; rg[49] = l_r;
        }
        __syncthreads();
        if (kh == 0) {
            float m1 = rg[48], l1 = rg[49];
            float m12 = fmaxf(m_r, m1);
            float f0 = __builtin_amdgcn_exp2f((m_r - m12) * SC2);
            float f1 = __builtin_amdgcn_exp2f((m1 - m12) * SC2);
            float inv = 1.f / (l_r * f0 + l1 * f1);
            int token = q0 + qg * 32 + lq;
#pragma unroll
            for (int db = 0; db < 3; db++) {
#pragma unroll
                for (int r = 0; r < 16; r++) {
                    int d = db * 32 + (r & 3) + 8 * (r >> 2) + 4 * hi;
                    if (d < HD) {
                        float own = (db == 0) ? o0[r] : (db == 1) ? o1[r] : o2[r];
                        float val = (own * f0 + rg[db * 16 + r] * f1) * inv;
                        unsigned short hb = f2bf(val);
                        float lo = val - bf2f(hb);
                        size_t a = (size_t)token * KP + head * HD + d;
                        ahi[a] = hb; alo[a] = f2bf(lo);
                    }
                }
            }
        }
    }
}

extern "C" void kernel_launch(void* const* d_in, const int* in_sizes, int n_in,
                              void* d_out, int out_size, void* d_ws, size_t ws_size,
                              hipStream_t stream) {
    const float* x      = (const float*)d_in[0];
    const float* w_qkv  = (const float*)d_in[1];
    const float* b_qkv  = (const float*)d_in[2];
    const float* w_proj = (const float*)d_in[3];
    const float* b_proj = (const float*)d_in[4];
    float* out = (float*)d_out;
    char* ws = (char*)d_ws;

    const size_t o_xb    = 0;
    const size_t o_wqkvb = o_xb    + 4456448;
    const size_t o_whi   = o_wqkvb + 1775616;
    const size_t o_wlo   = o_whi   + 591872;
    const size_t o_vtmp  = o_wlo   + 591872;
    const size_t o_qbf   = o_vtmp  + 4456448;
    const size_t o_kbf   = o_qbf   + 6291456;
    const size_t o_vt    = o_kbf   + 6291456;
    const size_t need    = o_vt + 6291456;
    if (ws_size < need) return;

    unsigned short* xb    = (unsigned short*)(ws + o_xb);
    unsigned short* wqkvb = (unsigned short*)(ws + o_wqkvb);
    unsigned short* whi   = (unsigned short*)(ws + o_whi);
    unsigned short* wlo   = (unsigned short*)(ws + o_wlo);
    unsigned short* vtmp  = (unsigned short*)(ws + o_vtmp);
    unsigned short* qbf   = (unsigned short*)(ws + o_qbf);
    unsigned short* kbf   = (unsigned short*)(ws + o_kbf);
    unsigned short* vt    = (unsigned short*)(ws + o_vt);
    unsigned short* ahi   = xb;
    unsigned short* alo   = vtmp;

    k_prep_all  <<<2048, 256, 0, stream>>>(x, w_qkv, w_proj, xb, wqkvb, whi, wlo, qbf, kbf);
    k_gemm_qkv  <<<dim3(N_TOK / 128, NQKVP / 96), 256, 0, stream>>>(xb, wqkvb, b_qkv, qbf, kbf, vtmp);
    k_reshape_v <<<dim3(N_TOK / 64, NH), 256, 0, stream>>>(vtmp, vt);
    k_attn2     <<<dim3(512), 512, 0, stream>>>(qbf, kbf, vt, ahi, alo);
    k_gemm_proj <<<dim3(N_TOK / 128, 9), 256, 0, stream>>>(ahi, alo, whi, wlo, b_proj, out);
}

// Round 7
// 129.428 us; speedup vs baseline: 1.6880x; 1.6880x over previous
//
#include <hip/hip_runtime.h>

typedef __attribute__((ext_vector_type(8))) short bf16x8;
typedef __attribute__((ext_vector_type(4))) float f32x4;
typedef __attribute__((ext_vector_type(16))) float f32x16;

#define DEV __device__ __forceinline__

static constexpr int N_TOK = 4096;
static constexpr int C     = 528;
static constexpr int NH    = 8;
static constexpr int HD    = 66;
static constexpr int HDP   = 96;    // q/k head-dim padded
static constexpr int VD96  = 96;    // v head-dim padded
static constexpr int KP    = 544;   // GEMM K padded (17*32)
static constexpr int NQKV  = 1584;
static constexpr int NQKVP = 1632;  // 17*96

DEV unsigned short f2bf(float f) {
    unsigned int u = __float_as_uint(f);
    u = (u + 0x7fffu + ((u >> 16) & 1u)) >> 16;
    return (unsigned short)u;
}
DEV float bf2f(unsigned short h) { return __uint_as_float(((unsigned int)h) << 16); }
DEV unsigned cvtpk2(float a, float b) {
    unsigned r;
    asm("v_cvt_pk_bf16_f32 %0, %1, %2" : "=v"(r) : "v"(a), "v"(b));
    return r;
}
DEV void plswap(unsigned &a, unsigned &b) {
    asm volatile("v_permlane32_swap_b32 %0, %1" : "+v"(a), "+v"(b));
}

// ---------------- fused prep: xb, wqkvb, whi/wlo, qb/kb pad-zeroing ----------------
__global__ void k_prep_all(const float* __restrict__ x, const float* __restrict__ w_qkv,
                           const float* __restrict__ w_proj,
                           unsigned short* __restrict__ xb, unsigned short* __restrict__ wqkvb,
                           unsigned short* __restrict__ whi, unsigned short* __restrict__ wlo,
                           unsigned short* __restrict__ qb, unsigned short* __restrict__ kbuf) {
    const int T0 = N_TOK * KP;
    const int T1 = T0 + NQKVP * KP;
    const int T2 = T1 + KP * KP;
    const int T3 = T2 + NH * N_TOK * (HDP - HD);
    for (int idx = blockIdx.x * 256 + threadIdx.x; idx < T3; idx += gridDim.x * 256) {
        if (idx < T0) {
            int n = idx / KP, k = idx - n * KP;
            xb[idx] = (k < C) ? f2bf(x[n * C + k]) : (unsigned short)0;
        } else if (idx < T1) {
            int j = idx - T0;
            int n = j / KP, k = j - n * KP;
            wqkvb[j] = (n < NQKV && k < C) ? f2bf(w_qkv[n * C + k]) : (unsigned short)0;
        } else if (idx < T2) {
            int j = idx - T1;
            int n = j / KP, k = j - n * KP;
            unsigned short hi = 0, lo = 0;
            if (n < C && k < C) {
                float v = w_proj[n * C + k];
                hi = f2bf(v);
                lo = f2bf(v - bf2f(hi));
            }
            whi[j] = hi; wlo[j] = lo;
        } else {
            int j = idx - T2;
            int n = j / 30, p = j - 30 * n;
            size_t a = (size_t)n * HDP + HD + p;
            qb[a] = 0; kbuf[a] = 0;
        }
    }
}

// ---------------- QKV GEMM (double-buffered); epilogue scatters q/k, writes v slab ----------------
__launch_bounds__(256)
__global__ void k_gemm_qkv(const unsigned short* __restrict__ A,
                           const unsigned short* __restrict__ B,
                           const float* __restrict__ bias,
                           unsigned short* __restrict__ qb, unsigned short* __restrict__ kbuf,
                           unsigned short* __restrict__ vtmp) {
    constexpr int LDA = 40;
    __shared__ unsigned short Al[2][128 * LDA];
    __shared__ unsigned short Bl[2][96 * LDA];
    int tid = threadIdx.x, lane = tid & 63, wid = tid >> 6;
    int m0 = blockIdx.x * 128, n0 = blockIdx.y * 96;
    int wm = (wid >> 1) * 64, wn = (wid & 1) * 48;
    int arow0 = tid >> 2, arow1 = (256 + tid) >> 2, akc = (tid & 3) * 8;
    bool bhave = tid < 128;
    int brow1 = (256 + tid) >> 2;
    f32x4 acc[4][3] = {};
    bf16x8 ra0, ra1, rb0, rb1;

    ra0 = *(const bf16x8*)&A[(size_t)(m0 + arow0) * KP + akc];
    ra1 = *(const bf16x8*)&A[(size_t)(m0 + arow1) * KP + akc];
    rb0 = *(const bf16x8*)&B[(size_t)(n0 + arow0) * KP + akc];
    if (bhave) rb1 = *(const bf16x8*)&B[(size_t)(n0 + brow1) * KP + akc];
    *(bf16x8*)&Al[0][arow0 * LDA + akc] = ra0;
    *(bf16x8*)&Al[0][arow1 * LDA + akc] = ra1;
    *(bf16x8*)&Bl[0][arow0 * LDA + akc] = rb0;
    if (bhave) *(bf16x8*)&Bl[0][brow1 * LDA + akc] = rb1;
    __syncthreads();

    int kk = (lane >> 4) * 8, cc = lane & 15;
    for (int kt = 0; kt < 17; kt++) {
        int cur = kt & 1;
        if (kt < 16) {
            int k0 = (kt + 1) * 32;
            ra0 = *(const bf16x8*)&A[(size_t)(m0 + arow0) * KP + k0 + akc];
            ra1 = *(const bf16x8*)&A[(size_t)(m0 + arow1) * KP + k0 + akc];
            rb0 = *(const bf16x8*)&B[(size_t)(n0 + arow0) * KP + k0 + akc];
            if (bhave) rb1 = *(const bf16x8*)&B[(size_t)(n0 + brow1) * KP + k0 + akc];
        }
        bf16x8 af[4], bfr[3];
#pragma unroll
        for (int mi = 0; mi < 4; mi++) af[mi] = *(const bf16x8*)&Al[cur][(wm + mi * 16 + cc) * LDA + kk];
#pragma unroll
        for (int ni = 0; ni < 3; ni++) bfr[ni] = *(const bf16x8*)&Bl[cur][(wn + ni * 16 + cc) * LDA + kk];
#pragma unroll
        for (int mi = 0; mi < 4; mi++)
#pragma unroll
            for (int ni = 0; ni < 3; ni++)
                acc[mi][ni] = __builtin_amdgcn_mfma_f32_16x16x32_bf16(af[mi], bfr[ni], acc[mi][ni], 0, 0, 0);
        if (kt < 16) {
            int nxt = cur ^ 1;
            *(bf16x8*)&Al[nxt][arow0 * LDA + akc] = ra0;
            *(bf16x8*)&Al[nxt][arow1 * LDA + akc] = ra1;
            *(bf16x8*)&Bl[nxt][arow0 * LDA + akc] = rb0;
            if (bhave) *(bf16x8*)&Bl[nxt][brow1 * LDA + akc] = rb1;
        }
        __syncthreads();
    }
#pragma unroll
    for (int mi = 0; mi < 4; mi++)
#pragma unroll
        for (int ni = 0; ni < 3; ni++)
#pragma unroll
            for (int r = 0; r < 4; r++) {
                int row = m0 + wm + mi * 16 + (lane >> 4) * 4 + r;
                int col = n0 + wn + ni * 16 + cc;
                float v = acc[mi][ni][r] + (col < NQKV ? bias[col] : 0.f);
                unsigned short b = f2bf(v);
                if (col < 2 * C) {
                    int d5 = (col >= C) ? col - C : col;
                    unsigned h = (unsigned)d5 / 66u;
                    int dd = d5 - 66 * (int)h;
                    size_t a = ((size_t)h * N_TOK + row) * HDP + dd;
                    if (col >= C) kbuf[a] = b; else qb[a] = b;
                } else if (col < NQKV) {
                    vtmp[(size_t)row * C + (col - 2 * C)] = b;
                }
            }
}

// ---------------- v transpose: vtmp[4096][528] -> vt[8][96][4096] ----------------
__global__ void k_reshape_v(const unsigned short* __restrict__ vtmp, unsigned short* __restrict__ vt) {
    __shared__ unsigned short lt[64 * 104];
    int h = blockIdx.y, n0 = blockIdx.x * 64, tid = threadIdx.x;
#pragma unroll
    for (int i = 0; i < 24; i++) {
        int idx = i * 256 + tid;
        int ni = idx / 96, d = idx - ni * 96;
        unsigned short v = 0;
        if (d < HD) v = vtmp[(size_t)(n0 + ni) * C + h * HD + d];
        lt[ni * 104 + d] = v;
    }
    __syncthreads();
#pragma unroll
    for (int i = 0; i < 24; i++) {
        int idx = i * 256 + tid;
        int d = idx >> 6, ni = idx & 63;
        vt[((size_t)h * VD96 + d) * N_TOK + n0 + ni] = lt[ni * 104 + d];
    }
}

// ---------------- flash attention: QBLK=128 (4 qg x 2 kh), KVBLK=128,
//                  single 56KB buffer + T14 reg prefetch -> 2 blocks/CU ----------------
__launch_bounds__(512, 2)
__global__ void k_attn(const unsigned short* __restrict__ qb,
                       const unsigned short* __restrict__ kb,
                       const unsigned short* __restrict__ vt,
                       unsigned short* __restrict__ ahi,
                       unsigned short* __restrict__ alo) {
    // K [128 keys][128 slots] (32KB) + V [96 d][128 slots] (24KB) = 56KB
    __shared__ __align__(16) unsigned short S[128 * 128 + 96 * 128];
    int tid = threadIdx.x, lane = tid & 63, wid = tid >> 6;
    int wq = wid & 3;            // q-group of 32 rows
    int kh = wid >> 2;           // key half [0,2): 64 keys each
    int hi = lane >> 5, lq = lane & 31;
    int bid = blockIdx.x;
    int head = bid & 7;          // head == XCD -> K/V L2-resident
    int q0 = (bid >> 3) * 128;
    const float SC2 = 0.12309149097933274f * 1.4426950408889634f;  // 66^-0.5 * log2(e)

    bf16x8 aq[6];
    {
        const unsigned short* qrow = qb + ((size_t)head * N_TOK + q0 + wq * 32 + lq) * HDP + hi * 8;
#pragma unroll
        for (int t = 0; t < 6; t++) aq[t] = *(const bf16x8*)&qrow[t * 16];
    }
    f32x16 o0 = {}, o1 = {}, o2 = {};
    float m_r = -3e38f, l_r = 0.f;

    const unsigned short* kg = kb + (size_t)head * N_TOK * HDP;
    const unsigned short* vg = vt + (size_t)head * VD96 * N_TOK;

    // staging: K 128x12=1536 chunks + V 96x16=1536 chunks = 3072 / 512 threads = 6 each (3K + 3V)
    const unsigned short* gpK[3];
    const unsigned short* gpV[3];
    int laK[3], laV[3];
#pragma unroll
    for (int j = 0; j < 3; j++) {
        int c = j * 512 + tid;
        int row = c / 12, ch = c - row * 12;
        gpK[j] = kg + (size_t)row * HDP + ch * 8;
        laK[j] = row * 128 + ((ch ^ (row & 15)) << 3);
        int row2 = c >> 4, ch2 = c & 15;
        gpV[j] = vg + (size_t)row2 * N_TOK + ch2 * 8;
        laV[j] = 128 * 128 + row2 * 128 + ((ch2 ^ (row2 & 15)) << 3);
    }
    // stage tile 0
#pragma unroll
    for (int j = 0; j < 3; j++) {
        *(bf16x8*)&S[laK[j]] = *(const bf16x8*)gpK[j];
        *(bf16x8*)&S[laV[j]] = *(const bf16x8*)gpV[j];
    }
    __syncthreads();

    for (int kt = 0; kt < 32; kt++) {
        // T14: issue next tile's loads now; publish after the read-drain barrier
        bf16x8 gk[3], gv[3];
        if (kt < 31) {
            size_t n1 = (size_t)(kt + 1) * 128;
#pragma unroll
            for (int j = 0; j < 3; j++) {
                gk[j] = *(const bf16x8*)(gpK[j] + n1 * HDP);
                gv[j] = *(const bf16x8*)(gpV[j] + n1);
            }
        }

        // S = K Q^T over this wave's 64-key half
        f32x16 s0 = {}, s1 = {};
        {
            int r0 = kh * 64 + lq, r1 = r0 + 32;
#pragma unroll
            for (int t = 0; t < 6; t++) {
                bf16x8 ka0 = *(const bf16x8*)&S[r0 * 128 + (((2 * t + hi) ^ (r0 & 15)) << 3)];
                bf16x8 ka1 = *(const bf16x8*)&S[r1 * 128 + (((2 * t + hi) ^ (r1 & 15)) << 3)];
                s0 = __builtin_amdgcn_mfma_f32_32x32x16_bf16(ka0, aq[t], s0, 0, 0, 0);
                s1 = __builtin_amdgcn_mfma_f32_32x32x16_bf16(ka1, aq[t], s1, 0, 0, 0);
            }
        }

        // online softmax with defer-rescale (T13)
        float mx = s0[0];
#pragma unroll
        for (int r = 1; r < 16; r++) mx = fmaxf(mx, s0[r]);
#pragma unroll
        for (int r = 0; r < 16; r++) mx = fmaxf(mx, s1[r]);
        mx = fmaxf(mx, __shfl_xor(mx, 32, 64));
        if (!__all((mx - m_r) * SC2 <= 8.f)) {
            float mnew = fmaxf(m_r, mx);
            float fct = __builtin_amdgcn_exp2f((m_r - mnew) * SC2);
            m_r = mnew;
            l_r *= fct;
#pragma unroll
            for (int r = 0; r < 16; r++) { o0[r] *= fct; o1[r] *= fct; o2[r] *= fct; }
        }
        float nb = m_r * SC2;
        float lsum = 0.f;
#pragma unroll
        for (int r = 0; r < 16; r++) { s0[r] = __builtin_amdgcn_exp2f(__builtin_fmaf(s0[r], SC2, -nb)); lsum += s0[r]; }
#pragma unroll
        for (int r = 0; r < 16; r++) { s1[r] = __builtin_amdgcn_exp2f(__builtin_fmaf(s1[r], SC2, -nb)); lsum += s1[r]; }
        lsum += __shfl_xor(lsum, 32, 64);
        l_r += lsum;

        // pack P into PV B-fragments: 16 cvt_pk + 8 permlane32_swap (T12)
        unsigned u0[2][4], u1[2][4];
#pragma unroll
        for (int a = 0; a < 4; a++) {
            u0[0][a] = cvtpk2(s0[4 * a + 0], s0[4 * a + 1]);
            u1[0][a] = cvtpk2(s0[4 * a + 2], s0[4 * a + 3]);
            u0[1][a] = cvtpk2(s1[4 * a + 0], s1[4 * a + 1]);
            u1[1][a] = cvtpk2(s1[4 * a + 2], s1[4 * a + 3]);
        }
#pragma unroll
        for (int kb2 = 0; kb2 < 2; kb2++)
#pragma unroll
            for (int a0 = 0; a0 < 4; a0 += 2) {
                plswap(u0[kb2][a0], u0[kb2][a0 + 1]);
                plswap(u1[kb2][a0], u1[kb2][a0 + 1]);
            }

        // O^T += V^T P over this wave's key half
#pragma unroll
        for (int t2 = 0; t2 < 4; t2++) {
            int kb2 = t2 >> 1, a0 = (t2 & 1) * 2;
            union { unsigned u[4]; bf16x8 v; } pf;
            pf.u[0] = u0[kb2][a0];     pf.u[1] = u1[kb2][a0];
            pf.u[2] = u0[kb2][a0 + 1]; pf.u[3] = u1[kb2][a0 + 1];
            int ch = kh * 8 + 2 * t2 + hi;
            int rv0 = lq, rv1 = 32 + lq, rv2 = 64 + lq;
            bf16x8 va0 = *(const bf16x8*)&S[128 * 128 + rv0 * 128 + ((ch ^ (rv0 & 15)) << 3)];
            bf16x8 va1 = *(const bf16x8*)&S[128 * 128 + rv1 * 128 + ((ch ^ (rv1 & 15)) << 3)];
            bf16x8 va2 = *(const bf16x8*)&S[128 * 128 + rv2 * 128 + ((ch ^ (rv2 & 15)) << 3)];
            o0 = __builtin_amdgcn_mfma_f32_32x32x16_bf16(va0, pf.v, o0, 0, 0, 0);
            o1 = __builtin_amdgcn_mfma_f32_32x32x16_bf16(va1, pf.v, o1, 0, 0, 0);
            o2 = __builtin_amdgcn_mfma_f32_32x32x16_bf16(va2, pf.v, o2, 0, 0, 0);
        }

        __syncthreads();            // all reads of current tile done
        if (kt < 31) {
#pragma unroll
            for (int j = 0; j < 3; j++) {
                *(bf16x8*)&S[laK[j]] = gk[j];
                *(bf16x8*)&S[laV[j]] = gv[j];
            }
        }
        __syncthreads();            // next tile published
    }

    // ---- combine key-half partials (kh=1 -> LDS, kh=0 merges & stores) ----
    float* xc = (float*)&S[0];      // 14336 floats capacity; usage (255)*52+49 = 13309
    float* rg = xc + (size_t)((wq * 64 + lane) * 52);
    if (kh == 1) {
#pragma unroll
        for (int r = 0; r < 16; r++) { rg[r] = o0[r]; rg[16 + r] = o1[r]; rg[32 + r] = o2[r]; }
        rg[48] = m_r; rg[49] = l_r;
    }
    __syncthreads();
    if (kh == 0) {
        float m1 = rg[48], l1 = rg[49];
        float m12 = fmaxf(m_r, m1);
        float f0 = __builtin_amdgcn_exp2f((m_r - m12) * SC2);
        float f1 = __builtin_amdgcn_exp2f((m1 - m12) * SC2);
        float inv = 1.f / (l_r * f0 + l1 * f1);
        int token = q0 + wq * 32 + lq;
#pragma unroll
        for (int db = 0; db < 3; db++) {
#pragma unroll
            for (int r = 0; r < 16; r++) {
                int d = db * 32 + (r & 3) + 8 * (r >> 2) + 4 * hi;
                if (d < HD) {
                    float own = (db == 0) ? o0[r] : (db == 1) ? o1[r] : o2[r];
                    float val = (own * f0 + rg[db * 16 + r] * f1) * inv;
                    unsigned short hb = f2bf(val);
                    float lo = val - bf2f(hb);
                    size_t a = (size_t)token * KP + head * HD + d;
                    ahi[a] = hb; alo[a] = f2bf(lo);
                }
            }
        }
    }
}

// ---------------- proj GEMM (split-precision, BN=64, double-buffered) ----------------
__launch_bounds__(256)
__global__ void k_gemm_proj(const unsigned short* __restrict__ Ahi_, const unsigned short* __restrict__ Alo_,
                            const unsigned short* __restrict__ Whi_, const unsigned short* __restrict__ Wlo_,
                            const float* __restrict__ bias, float* __restrict__ out) {
    constexpr int LDA = 40;
    __shared__ unsigned short Ah[2][128 * LDA], Aw[2][128 * LDA];
    __shared__ unsigned short Bh[2][64 * LDA],  Bw[2][64 * LDA];
    int tid = threadIdx.x, lane = tid & 63, wid = tid >> 6;
    int m0 = blockIdx.x * 128, n0 = blockIdx.y * 64;
    int wm = wid * 32;
    int arow0 = tid >> 2, arow1 = (256 + tid) >> 2, akc = (tid & 3) * 8;
    bool bok = (n0 + arow0) < KP;
    f32x4 acc[2][4] = {};
    bf16x8 rah0, rah1, ral0, ral1, rbh, rbl;
    const bf16x8 zero8 = {};

    rah0 = *(const bf16x8*)&Ahi_[(size_t)(m0 + arow0) * KP + akc];
    rah1 = *(const bf16x8*)&Ahi_[(size_t)(m0 + arow1) * KP + akc];
    ral0 = *(const bf16x8*)&Alo_[(size_t)(m0 + arow0) * KP + akc];
    ral1 = *(const bf16x8*)&Alo_[(size_t)(m0 + arow1) * KP + akc];
    rbh = bok ? *(const bf16x8*)&Whi_[(size_t)(n0 + arow0) * KP + akc] : zero8;
    rbl = bok ? *(const bf16x8*)&Wlo_[(size_t)(n0 + arow0) * KP + akc] : zero8;
    *(bf16x8*)&Ah[0][arow0 * LDA + akc] = rah0;
    *(bf16x8*)&Ah[0][arow1 * LDA + akc] = rah1;
    *(bf16x8*)&Aw[0][arow0 * LDA + akc] = ral0;
    *(bf16x8*)&Aw[0][arow1 * LDA + akc] = ral1;
    *(bf16x8*)&Bh[0][arow0 * LDA + akc] = rbh;
    *(bf16x8*)&Bw[0][arow0 * LDA + akc] = rbl;
    __syncthreads();

    int kk = (lane >> 4) * 8, cc = lane & 15;
    for (int kt = 0; kt < 17; kt++) {
        int cur = kt & 1;
        if (kt < 16) {
            int k0 = (kt + 1) * 32;
            rah0 = *(const bf16x8*)&Ahi_[(size_t)(m0 + arow0) * KP + k0 + akc];
            rah1 = *(const bf16x8*)&Ahi_[(size_t)(m0 + arow1) * KP + k0 + akc];
            ral0 = *(const bf16x8*)&Alo_[(size_t)(m0 + arow0) * KP + k0 + akc];
            ral1 = *(const bf16x8*)&Alo_[(size_t)(m0 + arow1) * KP + k0 + akc];
            rbh = bok ? *(const bf16x8*)&Whi_[(size_t)(n0 + arow0) * KP + k0 + akc] : zero8;
            rbl = bok ? *(const bf16x8*)&Wlo_[(size_t)(n0 + arow0) * KP + k0 + akc] : zero8;
        }
        bf16x8 ah[2], al[2], bh[4], bl[4];
#pragma unroll
        for (int mi = 0; mi < 2; mi++) {
            ah[mi] = *(const bf16x8*)&Ah[cur][(wm + mi * 16 + cc) * LDA + kk];
            al[mi] = *(const bf16x8*)&Aw[cur][(wm + mi * 16 + cc) * LDA + kk];
        }
#pragma unroll
        for (int ni = 0; ni < 4; ni++) {
            bh[ni] = *(const bf16x8*)&Bh[cur][(ni * 16 + cc) * LDA + kk];
            bl[ni] = *(const bf16x8*)&Bw[cur][(ni * 16 + cc) * LDA + kk];
        }
#pragma unroll
        for (int mi = 0; mi < 2; mi++)
#pragma unroll
            for (int ni = 0; ni < 4; ni++) {
                acc[mi][ni] = __builtin_amdgcn_mfma_f32_16x16x32_bf16(ah[mi], bh[ni], acc[mi][ni], 0, 0, 0);
                acc[mi][ni] = __builtin_amdgcn_mfma_f32_16x16x32_bf16(ah[mi], bl[ni], acc[mi][ni], 0, 0, 0);
                acc[mi][ni] = __builtin_amdgcn_mfma_f32_16x16x32_bf16(al[mi], bh[ni], acc[mi][ni], 0, 0, 0);
            }
        if (kt < 16) {
            int nxt = cur ^ 1;
            *(bf16x8*)&Ah[nxt][arow0 * LDA + akc] = rah0;
            *(bf16x8*)&Ah[nxt][arow1 * LDA + akc] = rah1;
            *(bf16x8*)&Aw[nxt][arow0 * LDA + akc] = ral0;
            *(bf16x8*)&Aw[nxt][arow1 * LDA + akc] = ral1;
            *(bf16x8*)&Bh[nxt][arow0 * LDA + akc] = rbh;
            *(bf16x8*)&Bw[nxt][arow0 * LDA + akc] = rbl;
        }
        __syncthreads();
    }
#pragma unroll
    for (int mi = 0; mi < 2; mi++)
#pragma unroll
        for (int ni = 0; ni < 4; ni++)
#pragma unroll
            for (int r = 0; r < 4; r++) {
                int row = m0 + wm + mi * 16 + (lane >> 4) * 4 + r;
                int col = n0 + ni * 16 + cc;
                if (col < C) out[(size_t)row * C + col] = acc[mi][ni][r] + bias[col];
            }
}

extern "C" void kernel_launch(void* const* d_in, const int* in_sizes, int n_in,
                              void* d_out, int out_size, void* d_ws, size_t ws_size,
                              hipStream_t stream) {
    const float* x      = (const float*)d_in[0];
    const float* w_qkv  = (const float*)d_in[1];
    const float* b_qkv  = (const float*)d_in[2];
    const float* w_proj = (const float*)d_in[3];
    const float* b_proj = (const float*)d_in[4];
    float* out = (float*)d_out;
    char* ws = (char*)d_ws;

    const size_t o_xb    = 0;
    const size_t o_wqkvb = o_xb    + 4456448;
    const size_t o_whi   = o_wqkvb + 1775616;
    const size_t o_wlo   = o_whi   + 591872;
    const size_t o_vtmp  = o_wlo   + 591872;
    const size_t o_qbf   = o_vtmp  + 4456448;
    const size_t o_kbf   = o_qbf   + 6291456;
    const size_t o_vt    = o_kbf   + 6291456;
    const size_t need    = o_vt + 6291456;
    if (ws_size < need) return;

    unsigned short* xb    = (unsigned short*)(ws + o_xb);
    unsigned short* wqkvb = (unsigned short*)(ws + o_wqkvb);
    unsigned short* whi   = (unsigned short*)(ws + o_whi);
    unsigned short* wlo   = (unsigned short*)(ws + o_wlo);
    unsigned short* vtmp  = (unsigned short*)(ws + o_vtmp);
    unsigned short* qbf   = (unsigned short*)(ws + o_qbf);
    unsigned short* kbf   = (unsigned short*)(ws + o_kbf);
    unsigned short* vt    = (unsigned short*)(ws + o_vt);
    unsigned short* ahi   = xb;
    unsigned short* alo   = vtmp;

    k_prep_all  <<<2048, 256, 0, stream>>>(x, w_qkv, w_proj, xb, wqkvb, whi, wlo, qbf, kbf);
    k_gemm_qkv  <<<dim3(N_TOK / 128, NQKVP / 96), 256, 0, stream>>>(xb, wqkvb, b_qkv, qbf, kbf, vtmp);
    k_reshape_v <<<dim3(N_TOK / 64, NH), 256, 0, stream>>>(vtmp, vt);
    k_attn      <<<dim3(256), 512, 0, stream>>>(qbf, kbf, vt, ahi, alo);
    k_gemm_proj <<<dim3(N_TOK / 128, 9), 256, 0, stream>>>(ahi, alo, whi, wlo, b_proj, out);
}